// Round 2
// baseline (232.754 us; speedup 1.0000x reference)
//
#include <hip/hip_runtime.h>
#include <stdint.h>

// Problem constants (B=2,S=2048 -> BS=4096). ALL inputs/outputs are FP32.
#define BSZ   4096    // B*S tokens
#define DIM   1024    // D
#define WTR   4096    // W trees
#define KDIM  4096    // GEMM K == W

typedef unsigned short u16;
typedef __attribute__((ext_vector_type(8))) short bhalf8;   // 8 x bf16 (4 VGPRs)
typedef __attribute__((ext_vector_type(4))) float floatx4;  // MFMA acc

__device__ __forceinline__ u16 f2bf(float f) {
    union { float f; uint32_t i; } v; v.f = f;
    uint32_t r = v.i + 0x7fffu + ((v.i >> 16) & 1u);   // round-nearest-even
    return (u16)(r >> 16);
}
// tanh(x) = 1 - 2/(exp2(x*2*log2e)+1) ; ~1e-6 abs err, saturates correctly
__device__ __forceinline__ float fast_tanh(float x) {
    float e = __builtin_amdgcn_exp2f(x * 2.885390081777927f);
    return fmaf(-2.0f, __builtin_amdgcn_rcpf(e + 1.0f), 1.0f);
}

// ---------------- kernel 1: selector softmax -> folded weights ----------------
// leaf_logits (W, 8, 11) f32 -> selw (W*8, 9) f32: [0..7]=softmax wts for slots,
// [8] = sel[10]-sel[8]  (basis constants are -1,0,1 -> fold into a bias)
__global__ __launch_bounds__(256) void k_selector(const float* __restrict__ ll,
                                                  float* __restrict__ selw) {
    int row = blockIdx.x * 256 + threadIdx.x;   // w*8 + leaf
    if (row >= WTR * 8) return;
    const float* p = ll + (size_t)row * 11;
    float v[11]; float m = -1e30f;
    #pragma unroll
    for (int c = 0; c < 11; ++c) { v[c] = p[c]; m = fmaxf(m, v[c]); }
    float s = 0.f;
    #pragma unroll
    for (int c = 0; c < 11; ++c) {
        v[c] = __builtin_amdgcn_exp2f((v[c] - m) * 1.4426950408889634f);
        s += v[c];
    }
    float inv = __builtin_amdgcn_rcpf(s);
    float* o = selw + (size_t)row * 9;
    #pragma unroll
    for (int c = 0; c < 8; ++c) o[c] = v[c] * inv;
    o[8] = (v[10] - v[8]) * inv;
}

// ------- kernel 2: transpose+convert out_w (W,D) f32 -> outwt (D,W) bf16 ------
__global__ __launch_bounds__(256) void k_transpose(const float* __restrict__ ow,
                                                   u16* __restrict__ owt) {
    __shared__ float tile[32][33];
    int d0 = blockIdx.x * 32, w0 = blockIdx.y * 32;
    int tx = threadIdx.x, ty = threadIdx.y;   // (32,8)
    #pragma unroll
    for (int i = 0; i < 32; i += 8)
        tile[ty + i][tx] = ow[(size_t)(w0 + ty + i) * DIM + d0 + tx];
    __syncthreads();
    #pragma unroll
    for (int i = 0; i < 32; i += 8)
        owt[(size_t)(d0 + ty + i) * WTR + w0 + tx] = f2bf(tile[tx][ty + i]);
}

// ---------------- kernel 3: basis = tanh(hidden @ slot_w + slot_b) ------------
// one block per token; basis stride 12 f32: [0..7]=slots, [8..10] = -1,0,1
__global__ __launch_bounds__(256) void k_basis(const float* __restrict__ hidden,
                                               const float* __restrict__ slot_w,
                                               const float* __restrict__ slot_b,
                                               float* __restrict__ basis) {
    int t = blockIdx.x, tid = threadIdx.x;
    int d0 = tid * 4;
    float4 hv = *(const float4*)(hidden + (size_t)t * DIM + d0);
    const float* wp = slot_w + (size_t)d0 * 8;   // row d has 8 f32 = 32B
    float4 wa[4], wb[4];                          // rows d0..d0+3, slots 0-3 / 4-7
    #pragma unroll
    for (int r = 0; r < 4; ++r) {
        wa[r] = *(const float4*)(wp + r * 8);
        wb[r] = *(const float4*)(wp + r * 8 + 4);
    }
    float h[4] = {hv.x, hv.y, hv.z, hv.w};
    float acc[8] = {0,0,0,0,0,0,0,0};
    #pragma unroll
    for (int r = 0; r < 4; ++r) {
        acc[0] = fmaf(h[r], wa[r].x, acc[0]);
        acc[1] = fmaf(h[r], wa[r].y, acc[1]);
        acc[2] = fmaf(h[r], wa[r].z, acc[2]);
        acc[3] = fmaf(h[r], wa[r].w, acc[3]);
        acc[4] = fmaf(h[r], wb[r].x, acc[4]);
        acc[5] = fmaf(h[r], wb[r].y, acc[5]);
        acc[6] = fmaf(h[r], wb[r].z, acc[6]);
        acc[7] = fmaf(h[r], wb[r].w, acc[7]);
    }
    #pragma unroll
    for (int off = 32; off >= 1; off >>= 1) {
        #pragma unroll
        for (int s = 0; s < 8; ++s) acc[s] += __shfl_down(acc[s], off, 64);
    }
    __shared__ float sm[4][8];
    int wid = tid >> 6, lane = tid & 63;
    if (lane == 0) {
        #pragma unroll
        for (int s = 0; s < 8; ++s) sm[wid][s] = acc[s];
    }
    __syncthreads();
    if (tid < 8) {
        float v = sm[0][tid] + sm[1][tid] + sm[2][tid] + sm[3][tid] + slot_b[tid];
        basis[t * 12 + tid] = fast_tanh(v);
    } else if (tid < 11) {
        basis[t * 12 + tid] = (float)(tid - 9);   // 8:-1, 9:0, 10:+1
    }
}

// ---------------- kernel 4: roots (einsum + tree) -> bf16 ---------------------
// thread = one tree w (selector weights live in 72 VGPRs), loop 64 tokens/block
#define TB 64
__global__ __launch_bounds__(256) void k_roots(const float* __restrict__ selw,
                                               const float* __restrict__ basis,
                                               const float* __restrict__ np_,
                                               u16* __restrict__ roots) {
    int w  = blockIdx.x * 256 + threadIdx.x;
    int t0 = blockIdx.y * TB;
    float lw = np_[0], rw = np_[1], pw = np_[2], dw = np_[3], nb = np_[4];
    float wv[72];
    const float4* sp = (const float4*)(selw + (size_t)w * 72);
    #pragma unroll
    for (int i = 0; i < 18; ++i) {
        float4 q = sp[i];
        wv[i*4] = q.x; wv[i*4+1] = q.y; wv[i*4+2] = q.z; wv[i*4+3] = q.w;
    }
    __shared__ float sb[TB * 12];
    for (int i = threadIdx.x; i < TB * 12; i += 256) sb[i] = basis[t0 * 12 + i];
    __syncthreads();
    for (int tt = 0; tt < TB; ++tt) {
        const float* bp = sb + tt * 12;
        float bb[8];
        #pragma unroll
        for (int s = 0; s < 8; ++s) bb[s] = bp[s];   // wave-broadcast LDS reads
        float v[8];
        #pragma unroll
        for (int l = 0; l < 8; ++l) {
            const float* ww = wv + l * 9;
            float a = ww[8];
            #pragma unroll
            for (int s = 0; s < 8; ++s) a = fmaf(ww[s], bb[s], a);
            v[l] = a;
        }
        #pragma unroll
        for (int lev = 0; lev < 3; ++lev) {
            int n = 4 >> lev;
            #pragma unroll
            for (int i = 0; i < 4; ++i) {
                if (i < n) {
                    float L = v[2*i], R = v[2*i+1];
                    float x = fmaf(lw, L, nb);
                    x = fmaf(rw, R, x);
                    x = fmaf(pw, L * R, x);
                    x = fmaf(dw, L - R, x);
                    v[i] = fast_tanh(x);
                }
            }
        }
        roots[(size_t)(t0 + tt) * WTR + w] = f2bf(v[0]);
    }
}

// ------- kernel 5: out = roots @ out_w + out_b  (bf16 MFMA, fp32 out) ---------
// A = roots (M=4096 x K=4096 bf16), Bt = outwt (N=1024 x K bf16)
// BM=128 BN=64 BK=32, 256 thr = 4 waves (2x2), wave tile 64x32 (4x2 mfma 16x16x32)
__device__ __forceinline__ void load16(const void* g, void* lds) {
    __builtin_amdgcn_global_load_lds(
        (const __attribute__((address_space(1))) uint32_t*)g,
        (__attribute__((address_space(3))) uint32_t*)lds, 16, 0, 0);
}

__global__ __launch_bounds__(256) void k_gemm(const u16* __restrict__ A,
                                              const u16* __restrict__ Bt,
                                              const float* __restrict__ out_b,
                                              float* __restrict__ C) {
    __shared__ __align__(16) u16 smA[128 * 32];   // 8KB, row-major [128][32]
    __shared__ __align__(16) u16 smB[64 * 32];    // 4KB, row-major [64][32]
    int tid = threadIdx.x;
    int bm = blockIdx.x * 128, bn = blockIdx.y * 64;
    int lane = tid & 63, wid = tid >> 6;
    int wm = (wid >> 1) * 64, wn = (wid & 1) * 32;

    floatx4 acc[4][2];
    #pragma unroll
    for (int i = 0; i < 4; ++i)
        #pragma unroll
        for (int j = 0; j < 2; ++j) acc[i][j] = (floatx4){0.f, 0.f, 0.f, 0.f};

    int ar = tid >> 2;                 // 0..63
    int ak = (tid & 3) * 8;            // k element offset
    const u16* gA = A  + (size_t)(bm + ar) * KDIM + ak;
    const u16* gB = Bt + (size_t)(bn + ar) * KDIM + ak;
    char* ldA = (char*)smA + tid * 16;
    char* ldB = (char*)smB + tid * 16;

    int col = lane & 15, quad = lane >> 4;
    int aoff = (wm + col) * 32 + quad * 8;   // element offsets into LDS tiles
    int boff = (wn + col) * 32 + quad * 8;

    for (int k0 = 0; k0 < KDIM; k0 += 32) {
        __syncthreads();                       // prev iter's ds_reads done
        load16(gA,              ldA);          // A rows 0..63
        load16(gA + 64 * KDIM,  ldA + 4096);   // A rows 64..127
        load16(gB,              ldB);          // B rows 0..63
        gA += 32; gB += 32;
        __syncthreads();                       // drains vmcnt before barrier

        bhalf8 af[4], bf[2];
        #pragma unroll
        for (int i = 0; i < 4; ++i)
            af[i] = *(const bhalf8*)(smA + aoff + i * 16 * 32);
        #pragma unroll
        for (int j = 0; j < 2; ++j)
            bf[j] = *(const bhalf8*)(smB + boff + j * 16 * 32);
        #pragma unroll
        for (int i = 0; i < 4; ++i)
            #pragma unroll
            for (int j = 0; j < 2; ++j)
                acc[i][j] = __builtin_amdgcn_mfma_f32_16x16x32_bf16(
                    af[i], bf[j], acc[i][j], 0, 0, 0);
    }

    #pragma unroll
    for (int j = 0; j < 2; ++j) {
        int n = bn + wn + j * 16 + col;
        float bv = out_b[n];
        #pragma unroll
        for (int i = 0; i < 4; ++i) {
            int m0 = bm + wm + i * 16 + quad * 4;
            #pragma unroll
            for (int r = 0; r < 4; ++r)
                C[(size_t)(m0 + r) * DIM + n] = acc[i][j][r] + bv;
        }
    }
}

// ---------------- launcher ----------------------------------------------------
extern "C" void kernel_launch(void* const* d_in, const int* in_sizes, int n_in,
                              void* d_out, int out_size, void* d_ws, size_t ws_size,
                              hipStream_t stream) {
    const float* hidden      = (const float*)d_in[0];
    const float* slot_w      = (const float*)d_in[1];
    const float* slot_b      = (const float*)d_in[2];
    const float* leaf_logits = (const float*)d_in[3];
    const float* node_params = (const float*)d_in[4];
    const float* out_w       = (const float*)d_in[5];
    const float* out_b       = (const float*)d_in[6];
    float* out = (float*)d_out;

    char* ws = (char*)d_ws;
    float* selw  = (float*)ws;                               // 4096*72*4  = 1179648 B
    float* basis = (float*)(ws + 1179648);                   // 4096*12*4  = 196608 B
    u16*   outwt = (u16*)(ws + 1179648 + 196608);            // 4096*1024*2= 8388608 B
    u16*   roots = (u16*)(ws + 1179648 + 196608 + 8388608);  // 4096*4096*2= 33554432 B

    k_selector <<<128, 256, 0, stream>>>(leaf_logits, selw);
    k_transpose<<<dim3(32, 128), dim3(32, 8), 0, stream>>>(out_w, outwt);
    k_basis    <<<BSZ, 256, 0, stream>>>(hidden, slot_w, slot_b, basis);
    k_roots    <<<dim3(WTR / 256, BSZ / TB), 256, 0, stream>>>(selw, basis, node_params, roots);
    k_gemm     <<<dim3(BSZ / 128, DIM / 64), 256, 0, stream>>>(roots, outwt, out_b, out);
}